// Round 6
// baseline (690.403 us; speedup 1.0000x reference)
//
#include <hip/hip_runtime.h>
#include <hip/hip_fp16.h>
#include <math.h>
#include <cstddef>

// Problem constants
#define H 256
#define NH 8
#define DH 32
#define LAYERS 2
#define BB 32
#define SS 512
#define FINDIM 199
#define AA 4
#define T_TOK (BB*SS)   // 16384 tokens
#define KIN 224         // padded input K (199 x + 3 tf + 22 zero)
#define TPB 64          // tokens per fused-kernel block

typedef unsigned short u16;
typedef unsigned int u32;
typedef __attribute__((ext_vector_type(8))) short short8;  // 8 bf16 (4 VGPRs)
typedef __attribute__((ext_vector_type(4))) float f4;      // MFMA C/D

__device__ __forceinline__ float b2f(u16 v){
  unsigned u = ((unsigned)v) << 16;
  return __builtin_bit_cast(float, u);
}
__device__ __forceinline__ u16 f2b(float f){
  unsigned u = __builtin_bit_cast(unsigned, f);
  unsigned r = (u + 0x7fffu + ((u >> 16) & 1u)) >> 16;   // RNE
  return (u16)r;
}
__device__ __forceinline__ float wave_sum(float v){
  #pragma unroll
  for (int mk=1; mk<64; mk<<=1) v += __shfl_xor(v, mk, 64);
  return v;
}

#define GLD_LDS16(g, l) \
  __builtin_amdgcn_global_load_lds((const __attribute__((address_space(1))) void*)(g), \
                                   (__attribute__((address_space(3))) void*)(l), 16, 0, 0)

#define SA (KIN+8)   // 232
#define SY (H+8)     // 264

// =========================================================================
// 64-token MFMA stage: 512 threads = 8 waves as 2(row)x4(col).
// =========================================================================
template<int KC, int WK>
__device__ __forceinline__ void stage_acc64(
    const u16* Xl, int sx, const u16* __restrict__ Wt,
    int r0, int c0, int l16, int lq, f4 acc[2][4])
{
  #pragma unroll
  for (int mi=0;mi<2;mi++)
    #pragma unroll
    for (int ni=0;ni<4;ni++) acc[mi][ni] = (f4){0.f,0.f,0.f,0.f};
  #pragma unroll
  for (int kc=0;kc<KC;kc++){
    short8 af[2], bf[4];
    #pragma unroll
    for (int mi=0;mi<2;mi++)
      af[mi] = *(const short8*)&Xl[(r0 + mi*16 + l16)*sx + kc*32 + lq*8];
    #pragma unroll
    for (int ni=0;ni<4;ni++)
      bf[ni] = *(const short8*)(Wt + (size_t)(c0 + ni*16 + l16)*WK + kc*32 + lq*8);
    #pragma unroll
    for (int mi=0;mi<2;mi++)
      #pragma unroll
      for (int ni=0;ni<4;ni++)
        acc[mi][ni] = __builtin_amdgcn_mfma_f32_16x16x32_bf16(af[mi], bf[ni], acc[mi][ni], 0,0,0);
  }
}

template<int DO_ELU>
__device__ __forceinline__ void stage_store64(
    f4 acc[2][4], const float* __restrict__ bias,
    int r0, int c0, int l16, int lq, u16* Yl, int sy)
{
  #pragma unroll
  for (int ni=0;ni<4;ni++){
    int col = c0 + ni*16 + l16;
    float bc = bias[col];
    #pragma unroll
    for (int mi=0;mi<2;mi++){
      #pragma unroll
      for (int r=0;r<4;r++){
        int row = r0 + mi*16 + lq*4 + r;
        float v = acc[mi][ni][r] + bc;
        if (DO_ELU) v = v > 0.f ? v : expm1f(v);
        Yl[row*sy + col] = f2b(v);
      }
    }
  }
}

// copy 64x256 bf16 tile global(stride H) -> LDS(stride sy), 512 threads
__device__ __forceinline__ void tile_load64(const u16* g, u16* Yl, int sy, int t){
  #pragma unroll
  for (int j=0;j<4;j++){
    int u = t + j*512;             // 2048 units of 8 u16
    int row = u >> 5, cu = u & 31;
    *(short8*)&Yl[row*sy + cu*8] = *(const short8*)(g + (size_t)row*H + cu*8);
  }
}

// LN over 64 LDS tile rows; wave w handles rows w*8..+7; lane covers 4 cols.
template<int WB>
__device__ __forceinline__ void tile_ln64(
    u16* Yl, int sy, const float* __restrict__ g, const float* __restrict__ b,
    u16* out, int t)
{
  int w = t >> 6, lane = t & 63;
  #pragma unroll
  for (int rr=0;rr<8;rr++){
    int row = w*8 + rr;
    float xv[4];
    #pragma unroll
    for (int j=0;j<4;j++) xv[j] = b2f(Yl[row*sy + lane*4 + j]);
    float s=0.f, ss=0.f;
    #pragma unroll
    for (int j=0;j<4;j++){ s += xv[j]; ss += xv[j]*xv[j]; }
    s = wave_sum(s); ss = wave_sum(ss);
    float mean = s * (1.0f/H);
    float var  = ss * (1.0f/H) - mean*mean;
    float rstd = rsqrtf(var + 1e-5f);
    ushort4 o;
    int col = lane*4;
    o.x = f2b((xv[0]-mean)*rstd*g[col+0] + b[col+0]);
    o.y = f2b((xv[1]-mean)*rstd*g[col+1] + b[col+1]);
    o.z = f2b((xv[2]-mean)*rstd*g[col+2] + b[col+2]);
    o.w = f2b((xv[3]-mean)*rstd*g[col+3] + b[col+3]);
    *(ushort4*)(out + (size_t)row*H + col) = o;
    if (WB && row == 63) *(ushort4*)(Yl + row*sy + col) = o;
  }
}

// =========================================================================
// Prepass kernels
// =========================================================================
struct WPtrs { const float* p[21]; };

__global__ __launch_bounds__(256) void wconv_kernel(WPtrs wp, u16* __restrict__ dst){
  __shared__ float tl[64][65];
  int mb = blockIdx.x >> 4, tile = blockIdx.x & 15;
  int k0 = (tile >> 2) * 64, n0 = (tile & 3) * 64;
  const float* src = wp.p[mb];
  int t = threadIdx.x;
  int r = t >> 4, cg = t & 15;
  #pragma unroll
  for (int p4=0;p4<4;p4++){
    f4 v = *(const f4*)(src + (size_t)(k0 + r + p4*16)*H + n0 + cg*4);
    tl[r+p4*16][cg*4+0]=v[0]; tl[r+p4*16][cg*4+1]=v[1];
    tl[r+p4*16][cg*4+2]=v[2]; tl[r+p4*16][cg*4+3]=v[3];
  }
  __syncthreads();
  u16* db = dst + (size_t)mb*H*H;
  #pragma unroll
  for (int p4=0;p4<4;p4++){
    int rn = r + p4*16;
    ushort4 o;
    o.x = f2b(tl[cg*4+0][rn]); o.y = f2b(tl[cg*4+1][rn]);
    o.z = f2b(tl[cg*4+2][rn]); o.w = f2b(tl[cg*4+3][rn]);
    *(ushort4*)(db + (size_t)(n0+rn)*H + k0 + cg*4) = o;
  }
}

__global__ __launch_bounds__(256) void wcat_kernel(
    const float* __restrict__ fp_w, const float* __restrict__ tp_w,
    u16* __restrict__ wcat){
  int idx = blockIdx.x*256 + threadIdx.x;   // n*224 + k
  if (idx >= 256*KIN) return;
  int n = idx / KIN, k2 = idx % KIN;
  float v = 0.f;
  if (k2 < FINDIM) v = fp_w[(size_t)k2*H + n];
  else if (k2 < FINDIM+3) v = tp_w[(size_t)(k2-FINDIM)*H + n];
  wcat[idx] = f2b(v);
}

__global__ __launch_bounds__(256) void xconv_kernel(
    const float* __restrict__ x, const float* __restrict__ tf,
    u16* __restrict__ ab){
  size_t idx = (size_t)blockIdx.x*256 + threadIdx.x;
  if (idx >= (size_t)T_TOK*KIN) return;
  int tok = idx / KIN, k2 = idx % KIN;
  float v = 0.f;
  if (k2 < FINDIM) v = x[(size_t)tok*FINDIM + k2];
  else if (k2 < FINDIM+3) v = tf[(size_t)tok*3 + (k2-FINDIM)];
  ab[idx] = f2b(v);
}

// =========================================================================
// input_kernel: hid = (Abuf@Wcat^T + (fp_b+tp_b)) @ ip_w + ip_b + PE
// =========================================================================
__global__ __launch_bounds__(512,2) void input_kernel(
    const u16* __restrict__ ab, const u16* __restrict__ wcat,
    const float* __restrict__ fp_b, const float* __restrict__ tp_b,
    const u16* __restrict__ ipw, const float* __restrict__ ip_b,
    u16* __restrict__ hid){
  __shared__ u16 Al[TPB*SA];
  __shared__ u16 Tl[TPB*SY];
  int t = threadIdx.x;
  int tok0 = blockIdx.x * TPB;
  int lane = t & 63, w = t >> 6;
  int l16 = lane & 15, lq = lane >> 4;
  int r0 = (w >> 2) * 32;
  int c0 = (w & 3) * 64;

  #pragma unroll
  for (int j=0;j<4;j++){
    int u = t + j*512;
    if (u < 1792){
      int row = u / 28, cu = u % 28;
      *(short8*)&Al[row*SA + cu*8] = *(const short8*)(ab + (size_t)(tok0+row)*KIN + cu*8);
    }
  }
  __syncthreads();

  f4 acc[2][4];
  stage_acc64<7, KIN>(Al, SA, wcat, r0, c0, l16, lq, acc);
  #pragma unroll
  for (int ni=0;ni<4;ni++){
    int col = c0 + ni*16 + l16;
    float bc = fp_b[col] + tp_b[col];
    #pragma unroll
    for (int mi=0;mi<2;mi++)
      #pragma unroll
      for (int r=0;r<4;r++){
        int row = r0 + mi*16 + lq*4 + r;
        Tl[row*SY + col] = f2b(acc[mi][ni][r] + bc);
      }
  }
  __syncthreads();

  stage_acc64<8, H>(Tl, SY, ipw, r0, c0, l16, lq, acc);
  #pragma unroll
  for (int ni=0;ni<4;ni++){
    int col = c0 + ni*16 + l16;
    float bc = ip_b[col];
    int ii = col >> 1;
    float div = __expf((float)(2*ii) * -0.03597789207803197f);
    #pragma unroll
    for (int mi=0;mi<2;mi++)
      #pragma unroll
      for (int r=0;r<4;r++){
        int row = r0 + mi*16 + lq*4 + r;
        int s = (tok0 + row) & (SS-1);
        float arg = (float)s * div;
        float pe = (col & 1) ? cosf(arg) : sinf(arg);
        hid[(size_t)(tok0+row)*H + col] = f2b(acc[mi][ni][r] + bc + pe);
      }
  }
}

// =========================================================================
// oproj_ln (+ optional aw-writer blocks): hid = LN(hid + ctx@wo + bo)*g+b.
// AW=1: grid has T_TOK/TPB + BB*NH blocks; the extra blocks (one per (b,h))
// recompute QK^T+exp, scale by saved 1/rowsum, and write aw (+ causal zeros)
// with nontemporal stores.  These blocks run concurrently with oproj compute
// on other CUs — 268 MB of writes overlap with MFMA work.
// =========================================================================
template<int AW>
__global__ __launch_bounds__(512,2) void oproj_ln_kernel(
    const u16* __restrict__ ctx, u16* __restrict__ hid,
    const u16* __restrict__ wo, const float* __restrict__ bo,
    const float* __restrict__ g, const float* __restrict__ b,
    const u16* __restrict__ q, const u16* __restrict__ k,
    const float* __restrict__ linv, float* __restrict__ aw){
  __shared__ u16 Xl[TPB*SY];
  __shared__ u16 Rl[TPB*SY];
  int bid = blockIdx.x;
  int t = threadIdx.x;
  int lane = t & 63, w = t >> 6;
  int l16 = lane & 15, lq = lane >> 4;

  if (AW && bid >= T_TOK/TPB){
    // ---- aw writer block: one per (b,h); wave w handles q-tile qt=w ----
    int bh = bid - T_TOK/TPB;
    int b2 = bh >> 3, h = bh & 7;
    const float scale = 0.17677669529663687f;
    float* ab = aw + (size_t)bh*SS*SS;
    int qt = w;
    #pragma unroll
    for (int s=0;s<4;s++){
      int qr0 = qt*64 + s*16;
      int KT  = qt*4 + s + 1;
      short8 af = *(const short8*)(q + ((size_t)(b2*SS + qr0 + l16))*H + h*DH + lq*8);
      float iv[4];
      #pragma unroll
      for (int i=0;i<4;i++) iv[i] = linv[(size_t)bh*SS + qr0 + lq*4 + i];
      for (int kt=0; kt<KT; kt++){
        short8 bfr = *(const short8*)(k + ((size_t)(b2*SS + kt*16 + l16))*H + h*DH + lq*8);
        f4 cc = (f4){0.f,0.f,0.f,0.f};
        cc = __builtin_amdgcn_mfma_f32_16x16x32_bf16(af, bfr, cc, 0,0,0);
        int col = kt*16 + l16;
        #pragma unroll
        for (int i=0;i<4;i++){
          int qi = qr0 + lq*4 + i;
          float val = (col <= qi) ? __expf(cc[i]*scale)*iv[i] : 0.f;
          __builtin_nontemporal_store(val, &ab[(size_t)qi*SS + col]);
        }
      }
      int c4base = KT*4;
      f4 z = (f4){0.f,0.f,0.f,0.f};
      #pragma unroll
      for (int ri=0;ri<4;ri++){
        int row = qr0 + ri*4 + lq;
        for (int j=l16; j < 128 - c4base; j += 16)
          __builtin_nontemporal_store(z, (f4*)&ab[(size_t)row*SS + (size_t)(c4base+j)*4]);
      }
    }
    return;
  }

  // ---- oproj + LN block ----
  int tok0 = bid * TPB;
  int r0 = (w >> 2) * 32;
  int c0 = (w & 3) * 64;
  u16* hb = hid + (size_t)tok0*H;

  tile_load64(ctx + (size_t)tok0*H, Xl, SY, t);
  tile_load64(hb, Rl, SY, t);
  __syncthreads();

  f4 acc[2][4];
  stage_acc64<8, H>(Xl, SY, wo, r0, c0, l16, lq, acc);
  __syncthreads();                 // all reads of Xl done before overwrite
  #pragma unroll
  for (int ni=0;ni<4;ni++){
    int col = c0 + ni*16 + l16;
    float bc = bo[col];
    #pragma unroll
    for (int mi=0;mi<2;mi++)
      #pragma unroll
      for (int r=0;r<4;r++){
        int row = r0 + mi*16 + lq*4 + r;
        float y = acc[mi][ni][r] + bc + b2f(Rl[row*SY + col]);
        Xl[row*SY + col] = f2b(y);
      }
  }
  __syncthreads();
  tile_ln64<0>(Xl, SY, g, b, hb, t);
}

// =========================================================================
// grn_kernel: hid = LN( (h2@gw+gb) * sigmoid(h2@ggw+ggb) + hid ) * lg + lb
// =========================================================================
template<int LOGITS>
__global__ __launch_bounds__(512,2) void grn_kernel(
    u16* __restrict__ hid,
    const u16* __restrict__ fc1, const u16* __restrict__ fc2,
    const u16* __restrict__ gw,  const u16* __restrict__ ggw,
    const float* __restrict__ b1, const float* __restrict__ b2,
    const float* __restrict__ gb, const float* __restrict__ ggb,
    const float* __restrict__ lg, const float* __restrict__ lb,
    const float* __restrict__ ow, const float* __restrict__ ob,
    float* __restrict__ lout){
  __shared__ u16 Xa[TPB*SY];
  __shared__ u16 Xb[TPB*SY];
  int t = threadIdx.x;
  int tok0 = blockIdx.x * TPB;
  int lane = t & 63, w = t >> 6;
  int l16 = lane & 15, lq = lane >> 4;
  int r0 = (w >> 2) * 32;
  int c0 = (w & 3) * 64;
  u16* hb = hid + (size_t)tok0*H;

  tile_load64(hb, Xa, SY, t);
  __syncthreads();

  f4 acc[2][4];
  stage_acc64<8, H>(Xa, SY, fc1, r0, c0, l16, lq, acc);   // h1 = ELU(x@fc1+b1)
  stage_store64<1>(acc, b1, r0, c0, l16, lq, Xb, SY);
  __syncthreads();
  stage_acc64<8, H>(Xb, SY, fc2, r0, c0, l16, lq, acc);   // h2 = ELU(h1@fc2+b2)
  __syncthreads();                                         // all h1 reads done
  stage_store64<1>(acc, b2, r0, c0, l16, lq, Xb, SY);     // h2 in place
  __syncthreads();

  stage_acc64<8, H>(Xb, SY, ggw, r0, c0, l16, lq, acc);   // gg
  u32 sgp[2][4][2];                                        // sigmoid(gg+ggb), f16x2 packed
  #pragma unroll
  for (int mi=0;mi<2;mi++)
    #pragma unroll
    for (int ni=0;ni<4;ni++){
      float bc = ggb[c0 + ni*16 + l16];
      float s0 = 1.0f/(1.0f + __expf(-(acc[mi][ni][0]+bc)));
      float s1 = 1.0f/(1.0f + __expf(-(acc[mi][ni][1]+bc)));
      float s2 = 1.0f/(1.0f + __expf(-(acc[mi][ni][2]+bc)));
      float s3 = 1.0f/(1.0f + __expf(-(acc[mi][ni][3]+bc)));
      sgp[mi][ni][0] = __builtin_bit_cast(u32, __floats2half2_rn(s0, s1));
      sgp[mi][ni][1] = __builtin_bit_cast(u32, __floats2half2_rn(s2, s3));
    }

  stage_acc64<8, H>(Xb, SY, gw, r0, c0, l16, lq, acc);    // g
  __syncthreads();                                         // all h2 reads done
  // y = (g+gb) * sig + x  -> Xb
  #pragma unroll
  for (int ni=0;ni<4;ni++){
    int col = c0 + ni*16 + l16;
    float bc = gb[col];
    #pragma unroll
    for (int mi=0;mi<2;mi++){
      float2 s01 = __half22float2(__builtin_bit_cast(__half2, sgp[mi][ni][0]));
      float2 s23 = __half22float2(__builtin_bit_cast(__half2, sgp[mi][ni][1]));
      float sv[4] = {s01.x, s01.y, s23.x, s23.y};
      #pragma unroll
      for (int r=0;r<4;r++){
        int row = r0 + mi*16 + lq*4 + r;
        float y = (acc[mi][ni][r] + bc) * sv[r] + b2f(Xa[row*SY + col]);
        Xb[row*SY + col] = f2b(y);
      }
    }
  }
  __syncthreads();
  tile_ln64<LOGITS>(Xb, SY, lg, lb, hb, t);

  if (LOGITS){
    if ((tok0 & (SS-1)) == SS - TPB){      // block holds token b*SS + SS-1 (local row 63)
      __syncthreads();
      if (t < 64){
        int bidx = tok0 >> 9;
        float a0=0.f, a1=0.f, a2=0.f, a3=0.f;
        #pragma unroll
        for (int j=0;j<4;j++){
          int k = t*4 + j;
          float xv = b2f(Xb[63*SY + k]);
          f4 wr = *(const f4*)(ow + (size_t)k*AA);
          a0 = fmaf(xv, wr[0], a0);
          a1 = fmaf(xv, wr[1], a1);
          a2 = fmaf(xv, wr[2], a2);
          a3 = fmaf(xv, wr[3], a3);
        }
        a0 = wave_sum(a0); a1 = wave_sum(a1);
        a2 = wave_sum(a2); a3 = wave_sum(a3);
        if (t == 0){
          lout[bidx*AA+0] = a0 + ob[0];
          lout[bidx*AA+1] = a1 + ob[1];
          lout[bidx*AA+2] = a2 + ob[2];
          lout[bidx*AA+3] = a3 + ob[3];
        }
      }
    }
  }
}

// =========================================================================
// QKV GEMM: 128x64 tile, global_load_lds, z-batched.
// =========================================================================
struct GemmJob  { const u16* Wt; const float* bias; u16* C; };
struct GemmBatch{ GemmJob j[3]; };

__global__ __launch_bounds__(256) void gemm_bf16(
    const u16* __restrict__ A, GemmBatch jb) {
  __shared__ u16 smem[128*64 + 64*64];
  u16* As  = smem;
  u16* Wsm = smem + 128*64;
  const GemmJob job = jb.j[blockIdx.z];
  const u16* Wt = job.Wt;
  int t = threadIdx.x;
  int m0 = blockIdx.x * 128;
  int n0 = blockIdx.y * 64;
  int lane = t & 63, w = t >> 6;
  int wr = (w >> 1) * 64;
  int wc = (w & 1) * 32;
  int l16 = lane & 15, lq = lane >> 4;

  f4 acc[4][2];
  #pragma unroll
  for (int mi=0;mi<4;mi++)
    #pragma unroll
    for (int ni=0;ni<2;ni++) acc[mi][ni] = (f4){0.f,0.f,0.f,0.f};

  for (int k0=0;k0<256;k0+=64){
    #pragma unroll
    for (int ja=0;ja<4;ja++){
      int ub = (w*4 + ja)*64;
      int u  = ub + lane;
      int m  = u >> 3, c = u & 7, kx = c ^ (m & 7);
      const u16* g = A + (size_t)(m0+m)*H + k0 + kx*8;
      GLD_LDS16(g, As + (size_t)ub*8);
    }
    #pragma unroll
    for (int jb2=0;jb2<2;jb2++){
      int ub = (w*2 + jb2)*64;
      int u  = ub + lane;
      int n  = u >> 3, c = u & 7, kx = c ^ (n & 7);
      const u16* g = Wt + (size_t)(n0+n)*H + k0 + kx*8;
      GLD_LDS16(g, Wsm + (size_t)ub*8);
    }
    __syncthreads();
    #pragma unroll
    for (int kc=0;kc<2;kc++){
      short8 af[4], bf[2];
      int kx = kc*4 + lq;
      #pragma unroll
      for (int mi=0;mi<4;mi++){
        int m = wr + mi*16 + l16;
        int un = (m<<3) | (kx ^ (m&7));
        af[mi] = *(short8*)&As[un*8];
      }
      #pragma unroll
      for (int ni=0;ni<2;ni++){
        int n = wc + ni*16 + l16;
        int un = (n<<3) | (kx ^ (n&7));
        bf[ni] = *(short8*)&Wsm[un*8];
      }
      #pragma unroll
      for (int mi=0;mi<4;mi++)
        #pragma unroll
        for (int ni=0;ni<2;ni++)
          acc[mi][ni] = __builtin_amdgcn_mfma_f32_16x16x32_bf16(af[mi], bf[ni], acc[mi][ni], 0,0,0);
    }
    __syncthreads();
  }

  u16* Cl = smem;
  #pragma unroll
  for (int ni=0;ni<2;ni++){
    int coll = wc + ni*16 + l16;
    float bcol = job.bias[n0 + coll];
    #pragma unroll
    for (int mi=0;mi<4;mi++){
      #pragma unroll
      for (int r=0;r<4;r++){
        int rowl = wr + mi*16 + lq*4 + r;
        Cl[rowl*68 + coll] = f2b(acc[mi][ni][r] + bcol);
      }
    }
  }
  __syncthreads();
  #pragma unroll
  for (int q2=0;q2<4;q2++){
    int u = q2*256 + t;
    int row = u >> 3, cu = u & 7;
    short8 val = *(short8*)&Cl[row*68 + cu*8];
    *(short8*)(job.C + (size_t)(m0+row)*H + n0 + cu*8) = val;
  }
}

// =========================================================================
// Fused causal attention, 8 waves/block: two q-tiles share one Vt stage.
// grid (4, BB*NH).  SAVE_L=1: store 1/rowsum to linv (aw written later,
// overlapped with oproj).  ctx goes to a separate buffer (Q/K preserved).
// =========================================================================
template<int SAVE_L>
__global__ __launch_bounds__(512) void attn_kernel(
    const u16* __restrict__ q, const u16* __restrict__ k,
    const u16* __restrict__ v, float* __restrict__ linv,
    u16* __restrict__ ctx) {
  __shared__ u16 Vt[DH][SS+8];
  __shared__ u16 Plds[8][16][72];
  int t  = threadIdx.x;
  int zg = blockIdx.x;          // 0..3
  int bh = blockIdx.y;
  int b  = bh >> 3, h = bh & 7;
  int lane = t & 63, w = t >> 6;
  int l16 = lane & 15, lq = lane >> 4;
  const float scale = 0.17677669529663687f;

  int nrows = (zg+1)*128;       // V rows needed by the deeper q-tile
  for (int kk = t; kk < nrows; kk += 512){
    const u16* vp = v + ((size_t)(b*SS + kk))*H + h*DH;
    short8 r0v = *(const short8*)(vp);
    short8 r1v = *(const short8*)(vp+8);
    short8 r2v = *(const short8*)(vp+16);
    short8 r3v = *(const short8*)(vp+24);
    #pragma unroll
    for (int j=0;j<8;j++){
      Vt[j][kk]    = (u16)r0v[j];
      Vt[8+j][kk]  = (u16)r1v[j];
      Vt[16+j][kk] = (u16)r2v[j];
      Vt[24+j][kk] = (u16)r3v[j];
    }
  }
  __syncthreads();

  {
    int qt  = zg*2 + (w >> 2);
    int wq  = w & 3;
    int qr0 = qt*64 + wq*16;
    int KT  = qt*4 + wq + 1;
    short8 af = *(const short8*)(q + ((size_t)(b*SS + qr0 + l16))*H + h*DH + lq*8);

    float l[4] = {0.f,0.f,0.f,0.f};
    f4 o[2] = {(f4){0.f,0.f,0.f,0.f}, (f4){0.f,0.f,0.f,0.f}};

    #pragma unroll
    for (int c8=0;c8<8;c8++){
      if (c8*4 < KT){
        #pragma unroll
        for (int j=0;j<4;j++){
          int kt = c8*4 + j;
          float p[4] = {0.f,0.f,0.f,0.f};
          if (kt < KT){
            short8 bfr = *(const short8*)(k + ((size_t)(b*SS + kt*16 + l16))*H + h*DH + lq*8);
            f4 cc = (f4){0.f,0.f,0.f,0.f};
            cc = __builtin_amdgcn_mfma_f32_16x16x32_bf16(af, bfr, cc, 0,0,0);
            int col = kt*16 + l16;
            #pragma unroll
            for (int i=0;i<4;i++){
              int qi = qr0 + lq*4 + i;
              float sc = (col <= qi) ? cc[i]*scale : -3.0e38f;
              p[i] = __expf(sc);
              l[i] += p[i];
            }
          }
          #pragma unroll
          for (int i=0;i<4;i++) Plds[w][lq*4+i][j*16+l16] = f2b(p[i]);
        }
        #pragma unroll
        for (int kc=0;kc<2;kc++){
          short8 pa = *(short8*)&Plds[w][l16][kc*32 + lq*8];
          #pragma unroll
          for (int dt=0;dt<2;dt++){
            short8 vb = *(const short8*)&Vt[dt*16 + l16][c8*64 + kc*32 + lq*8];
            o[dt] = __builtin_amdgcn_mfma_f32_16x16x32_bf16(pa, vb, o[dt], 0,0,0);
          }
        }
      }
    }

    #pragma unroll
    for (int i=0;i<4;i++){
      #pragma unroll
      for (int mk=1; mk<16; mk<<=1) l[i] += __shfl_xor(l[i], mk, 64);
    }
    float inv[4];
    #pragma unroll
    for (int i=0;i<4;i++) inv[i] = 1.0f / l[i];

    if (SAVE_L){
      if (l16 == 0){
        #pragma unroll
        for (int i=0;i<4;i++)
          linv[(size_t)bh*SS + qr0 + lq*4 + i] = inv[i];
      }
    }

    #pragma unroll
    for (int dt=0;dt<2;dt++){
      #pragma unroll
      for (int i=0;i<4;i++){
        int row = qr0 + lq*4 + i;
        ctx[((size_t)(b*SS + row))*H + h*DH + dt*16 + l16] = f2b(o[dt][i]*inv[i]);
      }
    }
  }
}

// -------------------------------------------------------------------------
extern "C" void kernel_launch(void* const* d_in, const int* in_sizes, int n_in,
                              void* d_out, int out_size, void* d_ws, size_t ws_size,
                              hipStream_t stream){
  (void)in_sizes; (void)n_in; (void)out_size; (void)ws_size;
  const float* x      = (const float*)d_in[0];
  const float* tf     = (const float*)d_in[1];
  const float* fp_w   = (const float*)d_in[2];
  const float* fp_b   = (const float*)d_in[3];
  const float* tp_w   = (const float*)d_in[4];
  const float* tp_b   = (const float*)d_in[5];
  const float* ip_w   = (const float*)d_in[6];
  const float* ip_b   = (const float*)d_in[7];
  const float* wq     = (const float*)d_in[8];
  const float* wk     = (const float*)d_in[9];
  const float* wv     = (const float*)d_in[10];
  const float* wo     = (const float*)d_in[11];
  const float* bq     = (const float*)d_in[12];
  const float* bk     = (const float*)d_in[13];
  const float* bv     = (const float*)d_in[14];
  const float* bo     = (const float*)d_in[15];
  const float* ln_g   = (const float*)d_in[16];
  const float* ln_b   = (const float*)d_in[17];
  const float* g_fc1w = (const float*)d_in[18];
  const float* g_fc2w = (const float*)d_in[19];
  const float* g_gw   = (const float*)d_in[20];
  const float* g_ggw  = (const float*)d_in[21];
  const float* g_fc1b = (const float*)d_in[22];
  const float* g_fc2b = (const float*)d_in[23];
  const float* g_gb   = (const float*)d_in[24];
  const float* g_ggb  = (const float*)d_in[25];
  const float* g_lg   = (const float*)d_in[26];
  const float* g_lb   = (const float*)d_in[27];
  const float* f_fc1w = (const float*)d_in[28];
  const float* f_fc2w = (const float*)d_in[29];
  const float* f_gw   = (const float*)d_in[30];
  const float* f_ggw  = (const float*)d_in[31];
  const float* f_fc1b = (const float*)d_in[32];
  const float* f_fc2b = (const float*)d_in[33];
  const float* f_gb   = (const float*)d_in[34];
  const float* f_ggb  = (const float*)d_in[35];
  const float* f_lg   = (const float*)d_in[36];
  const float* f_lb   = (const float*)d_in[37];
  const float* out_w  = (const float*)d_in[38];
  const float* out_b  = (const float*)d_in[39];

  float* logits = (float*)d_out;
  float* aw     = logits + BB*AA;

  // ws layout (u16): 21 weights | Wcat | Abuf | hid | buf1..4 | linv(f32)
  u16* wts = (u16*)d_ws;
  const size_t WMAT = (size_t)H*H;
  u16* wcat = wts  + 21*WMAT;
  u16* abuf = wcat + (size_t)H*KIN;
  u16* hid  = abuf + (size_t)T_TOK*KIN;
  size_t BUF = (size_t)T_TOK * H;
  u16* buf1 = hid  + BUF;
  u16* buf2 = buf1 + BUF;
  u16* buf3 = buf2 + BUF;
  u16* buf4 = buf3 + BUF;
  float* linv = (float*)(buf4 + BUF);   // BB*NH*SS floats = 512 KB

  WPtrs wp;
  wp.p[0]  = ip_w;
  wp.p[1]  = wq;        wp.p[2]  = wq + WMAT;
  wp.p[3]  = wk;        wp.p[4]  = wk + WMAT;
  wp.p[5]  = wv;        wp.p[6]  = wv + WMAT;
  wp.p[7]  = wo;        wp.p[8]  = wo + WMAT;
  wp.p[9]  = g_fc1w;    wp.p[10] = g_fc1w + WMAT;
  wp.p[11] = g_fc2w;    wp.p[12] = g_fc2w + WMAT;
  wp.p[13] = g_gw;      wp.p[14] = g_gw + WMAT;
  wp.p[15] = g_ggw;     wp.p[16] = g_ggw + WMAT;
  wp.p[17] = f_fc1w;    wp.p[18] = f_fc2w;
  wp.p[19] = f_gw;      wp.p[20] = f_ggw;
  const int WT_IP=0, WT_Q=1, WT_K=3, WT_V=5, WT_O=7,
            WT_FC1=9, WT_FC2=11, WT_GW=13, WT_GGW=15,
            WT_FFC1=17, WT_FFC2=18, WT_FGW=19, WT_FGGW=20;

  dim3 b256(256), b512(512);
  dim3 gAttn(4, BB*NH);
  dim3 gTok(T_TOK/TPB);                 // 256 blocks for fused token kernels

  wconv_kernel<<<21*16, b256, 0, stream>>>(wp, wts);
  wcat_kernel<<<(H*KIN+255)/256, b256, 0, stream>>>(fp_w, tp_w, wcat);
  xconv_kernel<<<(T_TOK*KIN+255)/256, b256, 0, stream>>>(x, tf, abuf);
  input_kernel<<<gTok, b512, 0, stream>>>(abuf, wcat, fp_b, tp_b,
                                          wts + (size_t)WT_IP*WMAT, ip_b, hid);

  for (int i=0;i<LAYERS;i++){
    const size_t BOFF = (size_t)i*H;
    GemmBatch gb;
    gb.j[0] = { wts + (size_t)(WT_Q+i)*WMAT, bq+BOFF, buf1 };
    gb.j[1] = { wts + (size_t)(WT_K+i)*WMAT, bk+BOFF, buf2 };
    gb.j[2] = { wts + (size_t)(WT_V+i)*WMAT, bv+BOFF, buf3 };
    gemm_bf16<<<dim3(T_TOK/128, H/64, 3), b256, 0, stream>>>(hid, gb);
    if (i == LAYERS-1){
      attn_kernel<1><<<gAttn, b512, 0, stream>>>(buf1, buf2, buf3, linv, buf4);
      oproj_ln_kernel<1><<<dim3(T_TOK/TPB + BB*NH), b512, 0, stream>>>(
          buf4, hid, wts + (size_t)(WT_O+i)*WMAT, bo+BOFF, ln_g+BOFF, ln_b+BOFF,
          buf1, buf2, linv, aw);
    } else {
      attn_kernel<0><<<gAttn, b512, 0, stream>>>(buf1, buf2, buf3, linv, buf4);
      oproj_ln_kernel<0><<<gTok, b512, 0, stream>>>(
          buf4, hid, wts + (size_t)(WT_O+i)*WMAT, bo+BOFF, ln_g+BOFF, ln_b+BOFF,
          nullptr, nullptr, nullptr, nullptr);
    }
    grn_kernel<0><<<gTok, b512, 0, stream>>>(hid,
        wts + (size_t)(WT_FC1+i)*WMAT, wts + (size_t)(WT_FC2+i)*WMAT,
        wts + (size_t)(WT_GW+i)*WMAT,  wts + (size_t)(WT_GGW+i)*WMAT,
        g_fc1b+BOFF, g_fc2b+BOFF, g_gb+BOFF, g_ggb+BOFF,
        g_lg+BOFF, g_lb+BOFF, nullptr, nullptr, nullptr);
  }

  grn_kernel<1><<<gTok, b512, 0, stream>>>(hid,
      wts + (size_t)WT_FFC1*WMAT, wts + (size_t)WT_FFC2*WMAT,
      wts + (size_t)WT_FGW*WMAT,  wts + (size_t)WT_FGGW*WMAT,
      f_fc1b, f_fc2b, f_gb, f_ggb, f_lg, f_lb,
      out_w, out_b, logits);
}

// Round 7
// 663.192 us; speedup vs baseline: 1.0410x; 1.0410x over previous
//
#include <hip/hip_runtime.h>
#include <hip/hip_fp16.h>
#include <math.h>
#include <cstddef>

// Problem constants
#define H 256
#define NH 8
#define DH 32
#define LAYERS 2
#define BB 32
#define SS 512
#define FINDIM 199
#define AA 4
#define T_TOK (BB*SS)   // 16384 tokens
#define KIN 224         // padded input K (199 x + 3 tf + 22 zero)
#define TPB 64          // tokens per fused-kernel block

typedef unsigned short u16;
typedef unsigned int u32;
typedef __attribute__((ext_vector_type(8))) short short8;  // 8 bf16 (4 VGPRs)
typedef __attribute__((ext_vector_type(4))) float f4;      // MFMA C/D

__device__ __forceinline__ float b2f(u16 v){
  unsigned u = ((unsigned)v) << 16;
  return __builtin_bit_cast(float, u);
}
__device__ __forceinline__ u16 f2b(float f){
  unsigned u = __builtin_bit_cast(unsigned, f);
  unsigned r = (u + 0x7fffu + ((u >> 16) & 1u)) >> 16;   // RNE
  return (u16)r;
}
__device__ __forceinline__ float wave_sum(float v){
  #pragma unroll
  for (int mk=1; mk<64; mk<<=1) v += __shfl_xor(v, mk, 64);
  return v;
}

#define GLD_LDS16(g, l) \
  __builtin_amdgcn_global_load_lds((const __attribute__((address_space(1))) void*)(g), \
                                   (__attribute__((address_space(3))) void*)(l), 16, 0, 0)

#define SA (KIN+8)   // 232
#define SY (H+8)     // 264

// =========================================================================
// 64-token MFMA stage: 512 threads = 8 waves as 2(row)x4(col).
// =========================================================================
template<int KC, int WK>
__device__ __forceinline__ void stage_acc64(
    const u16* Xl, int sx, const u16* __restrict__ Wt,
    int r0, int c0, int l16, int lq, f4 acc[2][4])
{
  #pragma unroll
  for (int mi=0;mi<2;mi++)
    #pragma unroll
    for (int ni=0;ni<4;ni++) acc[mi][ni] = (f4){0.f,0.f,0.f,0.f};
  #pragma unroll
  for (int kc=0;kc<KC;kc++){
    short8 af[2], bf[4];
    #pragma unroll
    for (int mi=0;mi<2;mi++)
      af[mi] = *(const short8*)&Xl[(r0 + mi*16 + l16)*sx + kc*32 + lq*8];
    #pragma unroll
    for (int ni=0;ni<4;ni++)
      bf[ni] = *(const short8*)(Wt + (size_t)(c0 + ni*16 + l16)*WK + kc*32 + lq*8);
    #pragma unroll
    for (int mi=0;mi<2;mi++)
      #pragma unroll
      for (int ni=0;ni<4;ni++)
        acc[mi][ni] = __builtin_amdgcn_mfma_f32_16x16x32_bf16(af[mi], bf[ni], acc[mi][ni], 0,0,0);
  }
}

template<int DO_ELU>
__device__ __forceinline__ void stage_store64(
    f4 acc[2][4], const float* __restrict__ bias,
    int r0, int c0, int l16, int lq, u16* Yl, int sy)
{
  #pragma unroll
  for (int ni=0;ni<4;ni++){
    int col = c0 + ni*16 + l16;
    float bc = bias[col];
    #pragma unroll
    for (int mi=0;mi<2;mi++){
      #pragma unroll
      for (int r=0;r<4;r++){
        int row = r0 + mi*16 + lq*4 + r;
        float v = acc[mi][ni][r] + bc;
        if (DO_ELU) v = v > 0.f ? v : expm1f(v);
        Yl[row*sy + col] = f2b(v);
      }
    }
  }
}

// copy 64x256 bf16 tile global(stride H) -> LDS(stride sy), 512 threads
__device__ __forceinline__ void tile_load64(const u16* g, u16* Yl, int sy, int t){
  #pragma unroll
  for (int j=0;j<4;j++){
    int u = t + j*512;             // 2048 units of 8 u16
    int row = u >> 5, cu = u & 31;
    *(short8*)&Yl[row*sy + cu*8] = *(const short8*)(g + (size_t)row*H + cu*8);
  }
}

// LN over 64 LDS tile rows; wave w handles rows w*8..+7; lane covers 4 cols.
template<int WB>
__device__ __forceinline__ void tile_ln64(
    u16* Yl, int sy, const float* __restrict__ g, const float* __restrict__ b,
    u16* out, int t)
{
  int w = t >> 6, lane = t & 63;
  #pragma unroll
  for (int rr=0;rr<8;rr++){
    int row = w*8 + rr;
    float xv[4];
    #pragma unroll
    for (int j=0;j<4;j++) xv[j] = b2f(Yl[row*sy + lane*4 + j]);
    float s=0.f, ss=0.f;
    #pragma unroll
    for (int j=0;j<4;j++){ s += xv[j]; ss += xv[j]*xv[j]; }
    s = wave_sum(s); ss = wave_sum(ss);
    float mean = s * (1.0f/H);
    float var  = ss * (1.0f/H) - mean*mean;
    float rstd = rsqrtf(var + 1e-5f);
    ushort4 o;
    int col = lane*4;
    o.x = f2b((xv[0]-mean)*rstd*g[col+0] + b[col+0]);
    o.y = f2b((xv[1]-mean)*rstd*g[col+1] + b[col+1]);
    o.z = f2b((xv[2]-mean)*rstd*g[col+2] + b[col+2]);
    o.w = f2b((xv[3]-mean)*rstd*g[col+3] + b[col+3]);
    *(ushort4*)(out + (size_t)row*H + col) = o;
    if (WB && row == 63) *(ushort4*)(Yl + row*sy + col) = o;
  }
}

// =========================================================================
// Prepass kernels
// =========================================================================
struct WPtrs { const float* p[21]; };

__global__ __launch_bounds__(256) void wconv_kernel(WPtrs wp, u16* __restrict__ dst){
  __shared__ float tl[64][65];
  int mb = blockIdx.x >> 4, tile = blockIdx.x & 15;
  int k0 = (tile >> 2) * 64, n0 = (tile & 3) * 64;
  const float* src = wp.p[mb];
  int t = threadIdx.x;
  int r = t >> 4, cg = t & 15;
  #pragma unroll
  for (int p4=0;p4<4;p4++){
    f4 v = *(const f4*)(src + (size_t)(k0 + r + p4*16)*H + n0 + cg*4);
    tl[r+p4*16][cg*4+0]=v[0]; tl[r+p4*16][cg*4+1]=v[1];
    tl[r+p4*16][cg*4+2]=v[2]; tl[r+p4*16][cg*4+3]=v[3];
  }
  __syncthreads();
  u16* db = dst + (size_t)mb*H*H;
  #pragma unroll
  for (int p4=0;p4<4;p4++){
    int rn = r + p4*16;
    ushort4 o;
    o.x = f2b(tl[cg*4+0][rn]); o.y = f2b(tl[cg*4+1][rn]);
    o.z = f2b(tl[cg*4+2][rn]); o.w = f2b(tl[cg*4+3][rn]);
    *(ushort4*)(db + (size_t)(n0+rn)*H + k0 + cg*4) = o;
  }
}

__global__ __launch_bounds__(256) void wcat_kernel(
    const float* __restrict__ fp_w, const float* __restrict__ tp_w,
    u16* __restrict__ wcat){
  int idx = blockIdx.x*256 + threadIdx.x;   // n*224 + k
  if (idx >= 256*KIN) return;
  int n = idx / KIN, k2 = idx % KIN;
  float v = 0.f;
  if (k2 < FINDIM) v = fp_w[(size_t)k2*H + n];
  else if (k2 < FINDIM+3) v = tp_w[(size_t)(k2-FINDIM)*H + n];
  wcat[idx] = f2b(v);
}

__global__ __launch_bounds__(256) void xconv_kernel(
    const float* __restrict__ x, const float* __restrict__ tf,
    u16* __restrict__ ab){
  size_t idx = (size_t)blockIdx.x*256 + threadIdx.x;
  if (idx >= (size_t)T_TOK*KIN) return;
  int tok = idx / KIN, k2 = idx % KIN;
  float v = 0.f;
  if (k2 < FINDIM) v = x[(size_t)tok*FINDIM + k2];
  else if (k2 < FINDIM+3) v = tf[(size_t)tok*3 + (k2-FINDIM)];
  ab[idx] = f2b(v);
}

// =========================================================================
// input_kernel: hid = (Abuf@Wcat^T + (fp_b+tp_b)) @ ip_w + ip_b + PE
// =========================================================================
__global__ __launch_bounds__(512,2) void input_kernel(
    const u16* __restrict__ ab, const u16* __restrict__ wcat,
    const float* __restrict__ fp_b, const float* __restrict__ tp_b,
    const u16* __restrict__ ipw, const float* __restrict__ ip_b,
    u16* __restrict__ hid){
  __shared__ u16 Al[TPB*SA];
  __shared__ u16 Tl[TPB*SY];
  int t = threadIdx.x;
  int tok0 = blockIdx.x * TPB;
  int lane = t & 63, w = t >> 6;
  int l16 = lane & 15, lq = lane >> 4;
  int r0 = (w >> 2) * 32;
  int c0 = (w & 3) * 64;

  #pragma unroll
  for (int j=0;j<4;j++){
    int u = t + j*512;
    if (u < 1792){
      int row = u / 28, cu = u % 28;
      *(short8*)&Al[row*SA + cu*8] = *(const short8*)(ab + (size_t)(tok0+row)*KIN + cu*8);
    }
  }
  __syncthreads();

  f4 acc[2][4];
  stage_acc64<7, KIN>(Al, SA, wcat, r0, c0, l16, lq, acc);
  #pragma unroll
  for (int ni=0;ni<4;ni++){
    int col = c0 + ni*16 + l16;
    float bc = fp_b[col] + tp_b[col];
    #pragma unroll
    for (int mi=0;mi<2;mi++)
      #pragma unroll
      for (int r=0;r<4;r++){
        int row = r0 + mi*16 + lq*4 + r;
        Tl[row*SY + col] = f2b(acc[mi][ni][r] + bc);
      }
  }
  __syncthreads();

  stage_acc64<8, H>(Tl, SY, ipw, r0, c0, l16, lq, acc);
  #pragma unroll
  for (int ni=0;ni<4;ni++){
    int col = c0 + ni*16 + l16;
    float bc = ip_b[col];
    int ii = col >> 1;
    float div = __expf((float)(2*ii) * -0.03597789207803197f);
    #pragma unroll
    for (int mi=0;mi<2;mi++)
      #pragma unroll
      for (int r=0;r<4;r++){
        int row = r0 + mi*16 + lq*4 + r;
        int s = (tok0 + row) & (SS-1);
        float arg = (float)s * div;
        float pe = (col & 1) ? cosf(arg) : sinf(arg);
        hid[(size_t)(tok0+row)*H + col] = f2b(acc[mi][ni][r] + bc + pe);
      }
  }
}

// =========================================================================
// oproj_ln: hid = LN(hid + ctx@wo + bo) * g + b   (one block = 64 tokens)
// =========================================================================
__global__ __launch_bounds__(512,2) void oproj_ln_kernel(
    const u16* __restrict__ ctx, u16* __restrict__ hid,
    const u16* __restrict__ wo, const float* __restrict__ bo,
    const float* __restrict__ g, const float* __restrict__ b){
  __shared__ u16 Xl[TPB*SY];
  __shared__ u16 Rl[TPB*SY];
  int t = threadIdx.x;
  int tok0 = blockIdx.x * TPB;
  int lane = t & 63, w = t >> 6;
  int l16 = lane & 15, lq = lane >> 4;
  int r0 = (w >> 2) * 32;
  int c0 = (w & 3) * 64;
  u16* hb = hid + (size_t)tok0*H;

  tile_load64(ctx + (size_t)tok0*H, Xl, SY, t);
  tile_load64(hb, Rl, SY, t);
  __syncthreads();

  f4 acc[2][4];
  stage_acc64<8, H>(Xl, SY, wo, r0, c0, l16, lq, acc);
  __syncthreads();                 // all reads of Xl done before overwrite
  #pragma unroll
  for (int ni=0;ni<4;ni++){
    int col = c0 + ni*16 + l16;
    float bc = bo[col];
    #pragma unroll
    for (int mi=0;mi<2;mi++)
      #pragma unroll
      for (int r=0;r<4;r++){
        int row = r0 + mi*16 + lq*4 + r;
        float y = acc[mi][ni][r] + bc + b2f(Rl[row*SY + col]);
        Xl[row*SY + col] = f2b(y);
      }
  }
  __syncthreads();
  tile_ln64<0>(Xl, SY, g, b, hb, t);
}

// =========================================================================
// grn_kernel: hid = LN( (h2@gw+gb) * sigmoid(h2@ggw+ggb) + hid ) * lg + lb
// =========================================================================
template<int LOGITS>
__global__ __launch_bounds__(512,2) void grn_kernel(
    u16* __restrict__ hid,
    const u16* __restrict__ fc1, const u16* __restrict__ fc2,
    const u16* __restrict__ gw,  const u16* __restrict__ ggw,
    const float* __restrict__ b1, const float* __restrict__ b2,
    const float* __restrict__ gb, const float* __restrict__ ggb,
    const float* __restrict__ lg, const float* __restrict__ lb,
    const float* __restrict__ ow, const float* __restrict__ ob,
    float* __restrict__ lout){
  __shared__ u16 Xa[TPB*SY];
  __shared__ u16 Xb[TPB*SY];
  int t = threadIdx.x;
  int tok0 = blockIdx.x * TPB;
  int lane = t & 63, w = t >> 6;
  int l16 = lane & 15, lq = lane >> 4;
  int r0 = (w >> 2) * 32;
  int c0 = (w & 3) * 64;
  u16* hb = hid + (size_t)tok0*H;

  tile_load64(hb, Xa, SY, t);
  __syncthreads();

  f4 acc[2][4];
  stage_acc64<8, H>(Xa, SY, fc1, r0, c0, l16, lq, acc);   // h1 = ELU(x@fc1+b1)
  stage_store64<1>(acc, b1, r0, c0, l16, lq, Xb, SY);
  __syncthreads();
  stage_acc64<8, H>(Xb, SY, fc2, r0, c0, l16, lq, acc);   // h2 = ELU(h1@fc2+b2)
  __syncthreads();                                         // all h1 reads done
  stage_store64<1>(acc, b2, r0, c0, l16, lq, Xb, SY);     // h2 in place
  __syncthreads();

  stage_acc64<8, H>(Xb, SY, ggw, r0, c0, l16, lq, acc);   // gg
  u32 sgp[2][4][2];                                        // sigmoid(gg+ggb), f16x2 packed
  #pragma unroll
  for (int mi=0;mi<2;mi++)
    #pragma unroll
    for (int ni=0;ni<4;ni++){
      float bc = ggb[c0 + ni*16 + l16];
      float s0 = 1.0f/(1.0f + __expf(-(acc[mi][ni][0]+bc)));
      float s1 = 1.0f/(1.0f + __expf(-(acc[mi][ni][1]+bc)));
      float s2 = 1.0f/(1.0f + __expf(-(acc[mi][ni][2]+bc)));
      float s3 = 1.0f/(1.0f + __expf(-(acc[mi][ni][3]+bc)));
      sgp[mi][ni][0] = __builtin_bit_cast(u32, __floats2half2_rn(s0, s1));
      sgp[mi][ni][1] = __builtin_bit_cast(u32, __floats2half2_rn(s2, s3));
    }

  stage_acc64<8, H>(Xb, SY, gw, r0, c0, l16, lq, acc);    // g
  __syncthreads();                                         // all h2 reads done
  // y = (g+gb) * sig + x  -> Xb
  #pragma unroll
  for (int ni=0;ni<4;ni++){
    int col = c0 + ni*16 + l16;
    float bc = gb[col];
    #pragma unroll
    for (int mi=0;mi<2;mi++){
      float2 s01 = __half22float2(__builtin_bit_cast(__half2, sgp[mi][ni][0]));
      float2 s23 = __half22float2(__builtin_bit_cast(__half2, sgp[mi][ni][1]));
      float sv[4] = {s01.x, s01.y, s23.x, s23.y};
      #pragma unroll
      for (int r=0;r<4;r++){
        int row = r0 + mi*16 + lq*4 + r;
        float y = (acc[mi][ni][r] + bc) * sv[r] + b2f(Xa[row*SY + col]);
        Xb[row*SY + col] = f2b(y);
      }
    }
  }
  __syncthreads();
  tile_ln64<LOGITS>(Xb, SY, lg, lb, hb, t);

  if (LOGITS){
    if ((tok0 & (SS-1)) == SS - TPB){      // block holds token b*SS + SS-1 (local row 63)
      __syncthreads();
      if (t < 64){
        int bidx = tok0 >> 9;
        float a0=0.f, a1=0.f, a2=0.f, a3=0.f;
        #pragma unroll
        for (int j=0;j<4;j++){
          int k = t*4 + j;
          float xv = b2f(Xb[63*SY + k]);
          f4 wr = *(const f4*)(ow + (size_t)k*AA);
          a0 = fmaf(xv, wr[0], a0);
          a1 = fmaf(xv, wr[1], a1);
          a2 = fmaf(xv, wr[2], a2);
          a3 = fmaf(xv, wr[3], a3);
        }
        a0 = wave_sum(a0); a1 = wave_sum(a1);
        a2 = wave_sum(a2); a3 = wave_sum(a3);
        if (t == 0){
          lout[bidx*AA+0] = a0 + ob[0];
          lout[bidx*AA+1] = a1 + ob[1];
          lout[bidx*AA+2] = a2 + ob[2];
          lout[bidx*AA+3] = a3 + ob[3];
        }
      }
    }
  }
}

// =========================================================================
// QKV GEMM: 128x64 tile, global_load_lds, z-batched.
// =========================================================================
struct GemmJob  { const u16* Wt; const float* bias; u16* C; };
struct GemmBatch{ GemmJob j[3]; };

__global__ __launch_bounds__(256) void gemm_bf16(
    const u16* __restrict__ A, GemmBatch jb) {
  __shared__ u16 smem[128*64 + 64*64];
  u16* As  = smem;
  u16* Wsm = smem + 128*64;
  const GemmJob job = jb.j[blockIdx.z];
  const u16* Wt = job.Wt;
  int t = threadIdx.x;
  int m0 = blockIdx.x * 128;
  int n0 = blockIdx.y * 64;
  int lane = t & 63, w = t >> 6;
  int wr = (w >> 1) * 64;
  int wc = (w & 1) * 32;
  int l16 = lane & 15, lq = lane >> 4;

  f4 acc[4][2];
  #pragma unroll
  for (int mi=0;mi<4;mi++)
    #pragma unroll
    for (int ni=0;ni<2;ni++) acc[mi][ni] = (f4){0.f,0.f,0.f,0.f};

  for (int k0=0;k0<256;k0+=64){
    #pragma unroll
    for (int ja=0;ja<4;ja++){
      int ub = (w*4 + ja)*64;
      int u  = ub + lane;
      int m  = u >> 3, c = u & 7, kx = c ^ (m & 7);
      const u16* g = A + (size_t)(m0+m)*H + k0 + kx*8;
      GLD_LDS16(g, As + (size_t)ub*8);
    }
    #pragma unroll
    for (int jb2=0;jb2<2;jb2++){
      int ub = (w*2 + jb2)*64;
      int u  = ub + lane;
      int n  = u >> 3, c = u & 7, kx = c ^ (n & 7);
      const u16* g = Wt + (size_t)(n0+n)*H + k0 + kx*8;
      GLD_LDS16(g, Wsm + (size_t)ub*8);
    }
    __syncthreads();
    #pragma unroll
    for (int kc=0;kc<2;kc++){
      short8 af[4], bf[2];
      int kx = kc*4 + lq;
      #pragma unroll
      for (int mi=0;mi<4;mi++){
        int m = wr + mi*16 + l16;
        int un = (m<<3) | (kx ^ (m&7));
        af[mi] = *(short8*)&As[un*8];
      }
      #pragma unroll
      for (int ni=0;ni<2;ni++){
        int n = wc + ni*16 + l16;
        int un = (n<<3) | (kx ^ (n&7));
        bf[ni] = *(short8*)&Wsm[un*8];
      }
      #pragma unroll
      for (int mi=0;mi<4;mi++)
        #pragma unroll
        for (int ni=0;ni<2;ni++)
          acc[mi][ni] = __builtin_amdgcn_mfma_f32_16x16x32_bf16(af[mi], bf[ni], acc[mi][ni], 0,0,0);
    }
    __syncthreads();
  }

  u16* Cl = smem;
  #pragma unroll
  for (int ni=0;ni<2;ni++){
    int coll = wc + ni*16 + l16;
    float bcol = job.bias[n0 + coll];
    #pragma unroll
    for (int mi=0;mi<4;mi++){
      #pragma unroll
      for (int r=0;r<4;r++){
        int rowl = wr + mi*16 + lq*4 + r;
        Cl[rowl*68 + coll] = f2b(acc[mi][ni][r] + bcol);
      }
    }
  }
  __syncthreads();
  #pragma unroll
  for (int q2=0;q2<4;q2++){
    int u = q2*256 + t;
    int row = u >> 3, cu = u & 7;
    short8 val = *(short8*)&Cl[row*68 + cu*8];
    *(short8*)(job.C + (size_t)(m0+row)*H + n0 + cu*8) = val;
  }
}

// =========================================================================
// Fused causal attention, split-KT: one q-tile per block (grid 8 x BB*NH),
// 512 threads.  Waves s and s+4 each handle half the c8 groups of sub-tile
// s, producing partial (l, o); partials combine through LDS (Plds reused as
// f32 scratch).  Critical path per wave: 32 -> 16 kt steps.
// WRITE_AW: recompute QK^T+exp in a 2nd pass, each wave over its own half.
// ctx overwrites q (each block writes only rows whose Q it holds in regs).
// =========================================================================
template<int WRITE_AW>
__global__ __launch_bounds__(512) void attn_kernel(
    const u16* __restrict__ q, const u16* __restrict__ k,
    const u16* __restrict__ v, float* __restrict__ aw,
    u16* __restrict__ ctx) {
  __shared__ u16 Vt[DH][SS+8];
  __shared__ u16 Plds[8][16][72];   // bf16 P tiles; reused as f32 combine buf
  int t  = threadIdx.x;
  int qt = blockIdx.x;              // 0..7, one 64-row q-tile per block
  int bh = blockIdx.y;
  int b  = bh >> 3, h = bh & 7;
  int lane = t & 63, w = t >> 6;
  int l16 = lane & 15, lq = lane >> 4;
  const float scale = 0.17677669529663687f;

  int nrows = (qt+1)*64;            // V rows this q-tile can attend to
  for (int kk = t; kk < nrows; kk += 512){
    const u16* vp = v + ((size_t)(b*SS + kk))*H + h*DH;
    short8 r0v = *(const short8*)(vp);
    short8 r1v = *(const short8*)(vp+8);
    short8 r2v = *(const short8*)(vp+16);
    short8 r3v = *(const short8*)(vp+24);
    #pragma unroll
    for (int j=0;j<8;j++){
      Vt[j][kk]    = (u16)r0v[j];
      Vt[8+j][kk]  = (u16)r1v[j];
      Vt[16+j][kk] = (u16)r2v[j];
      Vt[24+j][kk] = (u16)r3v[j];
    }
  }
  __syncthreads();

  int s   = w & 3;
  int qr0 = qt*64 + s*16;
  int KT  = qt*4 + s + 1;
  int G   = (KT + 3) >> 2;          // total c8 groups for this sub-tile
  int gh  = (G + 1) >> 1;           // split point
  int g0  = (w < 4) ? 0  : gh;
  int g1  = (w < 4) ? gh : G;
  short8 af = *(const short8*)(q + ((size_t)(b*SS + qr0 + l16))*H + h*DH + lq*8);

  float l[4] = {0.f,0.f,0.f,0.f};
  f4 o[2] = {(f4){0.f,0.f,0.f,0.f}, (f4){0.f,0.f,0.f,0.f}};

  for (int c8 = g0; c8 < g1; c8++){
    #pragma unroll
    for (int j=0;j<4;j++){
      int kt = c8*4 + j;
      float p[4] = {0.f,0.f,0.f,0.f};
      if (kt < KT){
        short8 bfr = *(const short8*)(k + ((size_t)(b*SS + kt*16 + l16))*H + h*DH + lq*8);
        f4 cc = (f4){0.f,0.f,0.f,0.f};
        cc = __builtin_amdgcn_mfma_f32_16x16x32_bf16(af, bfr, cc, 0,0,0);
        int col = kt*16 + l16;
        #pragma unroll
        for (int i=0;i<4;i++){
          int qi = qr0 + lq*4 + i;
          float sc = (col <= qi) ? cc[i]*scale : -3.0e38f;
          p[i] = __expf(sc);
          l[i] += p[i];
        }
      }
      #pragma unroll
      for (int i=0;i<4;i++) Plds[w][lq*4+i][j*16+l16] = f2b(p[i]);
    }
    #pragma unroll
    for (int kc=0;kc<2;kc++){
      short8 pa = *(short8*)&Plds[w][l16][kc*32 + lq*8];
      #pragma unroll
      for (int dt=0;dt<2;dt++){
        short8 vb = *(const short8*)&Vt[dt*16 + l16][c8*64 + kc*32 + lq*8];
        o[dt] = __builtin_amdgcn_mfma_f32_16x16x32_bf16(pa, vb, o[dt], 0,0,0);
      }
    }
  }

  // ---- combine partials (waves s+4 -> s) via Plds reinterpreted as f32 ----
  float* Pf = (float*)&Plds[0][0][0];   // 4 pairs x 64 lanes x 13 f32 = 13.3KB
  __syncthreads();                      // all Plds bf16 reads done
  if (w >= 4){
    float* dst = Pf + ((size_t)s*64 + lane)*13;
    #pragma unroll
    for (int i=0;i<4;i++) dst[i]   = l[i];
    #pragma unroll
    for (int i=0;i<4;i++) dst[4+i] = o[0][i];
    #pragma unroll
    for (int i=0;i<4;i++) dst[8+i] = o[1][i];
  }
  __syncthreads();
  float inv[4];
  if (w < 4){
    float* src = Pf + ((size_t)s*64 + lane)*13;
    #pragma unroll
    for (int i=0;i<4;i++) l[i]    += src[i];
    #pragma unroll
    for (int i=0;i<4;i++) o[0][i] += src[4+i];
    #pragma unroll
    for (int i=0;i<4;i++) o[1][i] += src[8+i];
    #pragma unroll
    for (int i=0;i<4;i++){
      #pragma unroll
      for (int mk=1; mk<16; mk<<=1) l[i] += __shfl_xor(l[i], mk, 64);
      inv[i] = 1.0f / l[i];
    }
    // ctx store (rows owned by this block)
    #pragma unroll
    for (int dt=0;dt<2;dt++){
      #pragma unroll
      for (int i=0;i<4;i++){
        int row = qr0 + lq*4 + i;
        ctx[((size_t)(b*SS + row))*H + h*DH + dt*16 + l16] = f2b(o[dt][i]*inv[i]);
      }
    }
    if (WRITE_AW){
      #pragma unroll
      for (int i=0;i<4;i++) src[i] = inv[i];   // broadcast inv to partner
    }
  }

  if (WRITE_AW){
    __syncthreads();
    if (w >= 4){
      const float* src = Pf + ((size_t)s*64 + lane)*13;
      #pragma unroll
      for (int i=0;i<4;i++) inv[i] = src[i];
    }
    float* ab = aw + (size_t)bh*SS*SS;
    int k_lo = g0*4;
    int k_hi = (g1*4 < KT) ? g1*4 : KT;
    for (int kt = k_lo; kt < k_hi; kt++){
      short8 bfr = *(const short8*)(k + ((size_t)(b*SS + kt*16 + l16))*H + h*DH + lq*8);
      f4 cc = (f4){0.f,0.f,0.f,0.f};
      cc = __builtin_amdgcn_mfma_f32_16x16x32_bf16(af, bfr, cc, 0,0,0);
      int col = kt*16 + l16;
      #pragma unroll
      for (int i=0;i<4;i++){
        int qi = qr0 + lq*4 + i;
        float val = (col <= qi) ? __expf(cc[i]*scale)*inv[i] : 0.f;
        __builtin_nontemporal_store(val, &ab[(size_t)qi*SS + col]);
      }
    }
    if (w >= 4){
      int c4base = KT*4;
      f4 z = (f4){0.f,0.f,0.f,0.f};
      #pragma unroll
      for (int ri=0;ri<4;ri++){
        int row = qr0 + ri*4 + lq;
        for (int j=l16; j < 128 - c4base; j += 16)
          __builtin_nontemporal_store(z, (f4*)&ab[(size_t)row*SS + (size_t)(c4base+j)*4]);
      }
    }
  }
}

// -------------------------------------------------------------------------
extern "C" void kernel_launch(void* const* d_in, const int* in_sizes, int n_in,
                              void* d_out, int out_size, void* d_ws, size_t ws_size,
                              hipStream_t stream){
  (void)in_sizes; (void)n_in; (void)out_size; (void)ws_size;
  const float* x      = (const float*)d_in[0];
  const float* tf     = (const float*)d_in[1];
  const float* fp_w   = (const float*)d_in[2];
  const float* fp_b   = (const float*)d_in[3];
  const float* tp_w   = (const float*)d_in[4];
  const float* tp_b   = (const float*)d_in[5];
  const float* ip_w   = (const float*)d_in[6];
  const float* ip_b   = (const float*)d_in[7];
  const float* wq     = (const float*)d_in[8];
  const float* wk     = (const float*)d_in[9];
  const float* wv     = (const float*)d_in[10];
  const float* wo     = (const float*)d_in[11];
  const float* bq     = (const float*)d_in[12];
  const float* bk     = (const float*)d_in[13];
  const float* bv     = (const float*)d_in[14];
  const float* bo     = (const float*)d_in[15];
  const float* ln_g   = (const float*)d_in[16];
  const float* ln_b   = (const float*)d_in[17];
  const float* g_fc1w = (const float*)d_in[18];
  const float* g_fc2w = (const float*)d_in[19];
  const float* g_gw   = (const float*)d_in[20];
  const float* g_ggw  = (const float*)d_in[21];
  const float* g_fc1b = (const float*)d_in[22];
  const float* g_fc2b = (const float*)d_in[23];
  const float* g_gb   = (const float*)d_in[24];
  const float* g_ggb  = (const float*)d_in[25];
  const float* g_lg   = (const float*)d_in[26];
  const float* g_lb   = (const float*)d_in[27];
  const float* f_fc1w = (const float*)d_in[28];
  const float* f_fc2w = (const float*)d_in[29];
  const float* f_gw   = (const float*)d_in[30];
  const float* f_ggw  = (const float*)d_in[31];
  const float* f_fc1b = (const float*)d_in[32];
  const float* f_fc2b = (const float*)d_in[33];
  const float* f_gb   = (const float*)d_in[34];
  const float* f_ggb  = (const float*)d_in[35];
  const float* f_lg   = (const float*)d_in[36];
  const float* f_lb   = (const float*)d_in[37];
  const float* out_w  = (const float*)d_in[38];
  const float* out_b  = (const float*)d_in[39];

  float* logits = (float*)d_out;
  float* aw     = logits + BB*AA;

  // ws layout (u16 units): 21 transposed weights | Wcat | Abuf | hid | buf1..3
  u16* wts = (u16*)d_ws;
  const size_t WMAT = (size_t)H*H;
  u16* wcat = wts  + 21*WMAT;
  u16* abuf = wcat + (size_t)H*KIN;
  u16* hid  = abuf + (size_t)T_TOK*KIN;
  size_t BUF = (size_t)T_TOK * H;
  u16* buf1 = hid  + BUF;
  u16* buf2 = buf1 + BUF;
  u16* buf3 = buf2 + BUF;

  WPtrs wp;
  wp.p[0]  = ip_w;
  wp.p[1]  = wq;        wp.p[2]  = wq + WMAT;
  wp.p[3]  = wk;        wp.p[4]  = wk + WMAT;
  wp.p[5]  = wv;        wp.p[6]  = wv + WMAT;
  wp.p[7]  = wo;        wp.p[8]  = wo + WMAT;
  wp.p[9]  = g_fc1w;    wp.p[10] = g_fc1w + WMAT;
  wp.p[11] = g_fc2w;    wp.p[12] = g_fc2w + WMAT;
  wp.p[13] = g_gw;      wp.p[14] = g_gw + WMAT;
  wp.p[15] = g_ggw;     wp.p[16] = g_ggw + WMAT;
  wp.p[17] = f_fc1w;    wp.p[18] = f_fc2w;
  wp.p[19] = f_gw;      wp.p[20] = f_ggw;
  const int WT_IP=0, WT_Q=1, WT_K=3, WT_V=5, WT_O=7,
            WT_FC1=9, WT_FC2=11, WT_GW=13, WT_GGW=15,
            WT_FFC1=17, WT_FFC2=18, WT_FGW=19, WT_FGGW=20;

  dim3 b256(256), b512(512);
  dim3 gAttn(8, BB*NH);
  dim3 gTok(T_TOK/TPB);                 // 256 blocks for fused token kernels

  wconv_kernel<<<21*16, b256, 0, stream>>>(wp, wts);
  wcat_kernel<<<(H*KIN+255)/256, b256, 0, stream>>>(fp_w, tp_w, wcat);
  xconv_kernel<<<(T_TOK*KIN+255)/256, b256, 0, stream>>>(x, tf, abuf);
  input_kernel<<<gTok, b512, 0, stream>>>(abuf, wcat, fp_b, tp_b,
                                          wts + (size_t)WT_IP*WMAT, ip_b, hid);

  for (int i=0;i<LAYERS;i++){
    const size_t BOFF = (size_t)i*H;
    GemmBatch gb;
    gb.j[0] = { wts + (size_t)(WT_Q+i)*WMAT, bq+BOFF, buf1 };
    gb.j[1] = { wts + (size_t)(WT_K+i)*WMAT, bk+BOFF, buf2 };
    gb.j[2] = { wts + (size_t)(WT_V+i)*WMAT, bv+BOFF, buf3 };
    gemm_bf16<<<dim3(T_TOK/128, H/64, 3), b256, 0, stream>>>(hid, gb);
    if (i == LAYERS-1)
      attn_kernel<1><<<gAttn, b512, 0, stream>>>(buf1, buf2, buf3, aw, buf1);
    else
      attn_kernel<0><<<gAttn, b512, 0, stream>>>(buf1, buf2, buf3, aw, buf1);
    oproj_ln_kernel<<<gTok, b512, 0, stream>>>(buf1, hid,
        wts + (size_t)(WT_O+i)*WMAT, bo+BOFF, ln_g+BOFF, ln_b+BOFF);
    grn_kernel<0><<<gTok, b512, 0, stream>>>(hid,
        wts + (size_t)(WT_FC1+i)*WMAT, wts + (size_t)(WT_FC2+i)*WMAT,
        wts + (size_t)(WT_GW+i)*WMAT,  wts + (size_t)(WT_GGW+i)*WMAT,
        g_fc1b+BOFF, g_fc2b+BOFF, g_gb+BOFF, g_ggb+BOFF,
        g_lg+BOFF, g_lb+BOFF, nullptr, nullptr, nullptr);
  }

  grn_kernel<1><<<gTok, b512, 0, stream>>>(hid,
      wts + (size_t)WT_FFC1*WMAT, wts + (size_t)WT_FFC2*WMAT,
      wts + (size_t)WT_FGW*WMAT,  wts + (size_t)WT_FGGW*WMAT,
      f_fc1b, f_fc2b, f_gb, f_ggb, f_lg, f_lb,
      out_w, out_b, logits);
}